// Round 2
// baseline (7513.603 us; speedup 1.0000x reference)
//
#include <hip/hip_runtime.h>

#define T_DIM 256
#define B_DIM 128
#define F_DIM 1024
#define G_DIM 4096
#define CHUNK 32
#define NCHUNK 8
#define NWGS 256

typedef short bf8  __attribute__((ext_vector_type(8)));
typedef float f32x4 __attribute__((ext_vector_type(4)));

// ---- ws layout (bytes) ----
#define OFF_CTRL  0ull
#define OFF_WIP   1024ull
#define SZ_WPACK  (8ull*1024*1024)      // 256nt * 32kt * 64lane * 8 * 2B
#define OFF_WHP   (OFF_WIP + SZ_WPACK)
#define OFF_XP    (OFF_WHP + SZ_WPACK)  // chunk: 32t*32kt*8mt*64*8 *2B = 8 MB
#define OFF_XWP   (OFF_XP + SZ_WPACK)   // chunk: 32t*8tm*256tn*64lane*4 *2B = 32 MB
#define SZ_XWP    (32ull*1024*1024)
#define OFF_HP    (OFF_XWP + SZ_XWP)    // 2 * 131072 * 2B
#define OFF_CBUF  (OFF_HP + 2ull*131072ull*2ull)   // 131072 * 4B
#define WS_NEED   (OFF_CBUF + 131072ull*4ull)

__device__ __forceinline__ unsigned short f2bf(float v) {
  union { float f; unsigned int u; } c; c.f = v;
  unsigned int u = c.u;
  return (unsigned short)((u + 0x7fffu + ((u >> 16) & 1u)) >> 16);  // RNE
}
__device__ __forceinline__ float bf2f(unsigned short u) {
  union { unsigned int i; float f; } c; c.i = ((unsigned int)u) << 16;
  return c.f;
}
__device__ __forceinline__ float sigm(float x)  { return 1.f / (1.f + __expf(-x)); }
__device__ __forceinline__ float tanh_(float x) { return 1.f - 2.f / (1.f + __expf(2.f * x)); }

// ---- pack W (fp32 F x 4F) -> MFMA-B frag order bf16: frag idx (nt*32+kt)*64+lane ----
__global__ __launch_bounds__(256) void pack_w(const float* __restrict__ Wi,
                                              const float* __restrict__ Wh,
                                              unsigned short* __restrict__ wip,
                                              unsigned short* __restrict__ whp) {
  int gid = blockIdx.x * 256 + threadIdx.x;
  const float* src = (gid >= 524288) ? Wh : Wi;
  unsigned short* dst = (gid >= 524288) ? whp : wip;
  int r  = gid & 524287;
  int nt = r >> 11;
  int kt = (r >> 6) & 31;
  int l  = r & 63;
  int col = nt * 16 + (l & 15);
  int k0  = kt * 32 + ((l >> 4) << 3);
  bf8 v8;
#pragma unroll
  for (int j = 0; j < 8; ++j)
    v8[j] = (short)f2bf(src[(size_t)(k0 + j) * G_DIM + col]);
  *reinterpret_cast<bf8*>(dst + (size_t)r * 8) = v8;
}

// ---- pack x chunk (32 steps, fp32) -> A-frag order: [tc][kt][mt8][lane][8] ----
__global__ __launch_bounds__(256) void pack_x_chunk(const float* __restrict__ xc,
                                                    unsigned short* __restrict__ xp) {
  int gid = blockIdx.x * 256 + threadIdx.x;   // 32*16384 = 524288
  int t  = gid >> 14;
  int r  = gid & 16383;
  int kt = r >> 9;
  int m  = (r >> 6) & 7;
  int l  = r & 63;
  int b  = m * 16 + (l & 15);
  int f0 = kt * 32 + ((l >> 4) << 3);
  const float* s = xc + ((size_t)(t * B_DIM + b)) * F_DIM + f0;
  bf8 v8;
#pragma unroll
  for (int j = 0; j < 8; ++j) v8[j] = (short)f2bf(s[j]);
  *reinterpret_cast<bf8*>(xp + (size_t)gid * 8) = v8;
}

__global__ __launch_bounds__(256) void pack_h(const float* __restrict__ h0,
                                              unsigned short* __restrict__ hp) {
  int gid = blockIdx.x * 256 + threadIdx.x;   // 16384
  int kt = gid >> 9;
  int m  = (gid >> 6) & 7;
  int l  = gid & 63;
  int b  = m * 16 + (l & 15);
  int f0 = kt * 32 + ((l >> 4) << 3);
  const float* s = h0 + (size_t)b * F_DIM + f0;
  bf8 v8;
#pragma unroll
  for (int j = 0; j < 8; ++j) v8[j] = (short)f2bf(s[j]);
  *reinterpret_cast<bf8*>(hp + (size_t)gid * 8) = v8;
}

// ---- Phase A: xW chunk GEMM, Wi slice in registers ----
// grid 256: WG=(fg=bid&63, ms4=bid>>6). wave=(gh=wv>>1, mtl=wv&1).
__global__ __launch_bounds__(256, 1) void xw_gemm(const unsigned short* __restrict__ xp,
                                                  const unsigned short* __restrict__ wip,
                                                  unsigned short* __restrict__ xwp) {
  int fg  = blockIdx.x & 63, ms4 = blockIdx.x >> 6;
  int tid = threadIdx.x, wv = tid >> 6, lane = tid & 63;
  int gh  = wv >> 1, mtl = wv & 1;

  bf8 br0[32], br1[32];
  {
    const bf8* w0 = reinterpret_cast<const bf8*>(wip) + (size_t)((gh*2+0)*64 + fg)*2048 + lane;
    const bf8* w1 = reinterpret_cast<const bf8*>(wip) + (size_t)((gh*2+1)*64 + fg)*2048 + lane;
#pragma unroll
    for (int kt = 0; kt < 32; ++kt) { br0[kt] = w0[kt*64]; br1[kt] = w1[kt*64]; }
  }
  const bf8* xpf = reinterpret_cast<const bf8*>(xp);
  ushort4* xw4 = reinterpret_cast<ushort4*>(xwp);

  for (int i = 0; i < 32; ++i) {
    int pairIdx = ms4 + 4*i;            // 0..127
    int tm = pairIdx*2 + mtl;           // 0..255
    int tc = tm >> 3, mt8 = tm & 7;
    const bf8* ap = xpf + (size_t)tc*16384 + mt8*64 + lane;
    f32x4 a0 = {0,0,0,0}, a1 = {0,0,0,0};
#pragma unroll
    for (int kt = 0; kt < 32; ++kt) {
      bf8 a = ap[kt*512];
      a0 = __builtin_amdgcn_mfma_f32_16x16x32_bf16(a, br0[kt], a0, 0, 0, 0);
      a1 = __builtin_amdgcn_mfma_f32_16x16x32_bf16(a, br1[kt], a1, 0, 0, 0);
    }
#pragma unroll
    for (int ntl = 0; ntl < 2; ++ntl) {
      int g = gh*2 + ntl;
      int tn = g*64 + fg;
      f32x4 v = ntl ? a1 : a0;
      ushort4 w;
      w.x = f2bf(v[0]); w.y = f2bf(v[1]); w.z = f2bf(v[2]); w.w = f2bf(v[3]);
      xw4[((size_t)(tc*8 + mt8)*256 + tn)*64 + lane] = w;
    }
  }
}

// ---- persistent-per-chunk scan: 256 WGs x 256 thr, Wh in registers ----
__global__ __launch_bounds__(256, 1) void lstm_scan(
    const unsigned short* __restrict__ xwp,
    const unsigned short* __restrict__ whp,
    unsigned short* __restrict__ hp,
    const float* __restrict__ bias,
    const int*   __restrict__ term,
    float* __restrict__ cbuf,
    float* __restrict__ out,
    unsigned int* __restrict__ ctrl, int t0) {
  __shared__ float part[2][2][16][17];   // [mtl][gate-2][row][col]

  int fg  = blockIdx.x & 63, mq4 = blockIdx.x >> 6;
  int tid = threadIdx.x, wv = tid >> 6, lane = tid & 63;
  int gh  = wv >> 1, mtl = wv & 1;
  int tm  = mq4*2 + mtl;                 // 0..7 (global 16-row tile)
  int fi  = fg*16 + (lane & 15);
  int bl0 = (lane >> 4) << 2;

  bf8 br0[32], br1[32];
  {
    const bf8* w0 = reinterpret_cast<const bf8*>(whp) + (size_t)((gh*2+0)*64 + fg)*2048 + lane;
    const bf8* w1 = reinterpret_cast<const bf8*>(whp) + (size_t)((gh*2+1)*64 + fg)*2048 + lane;
#pragma unroll
    for (int kt = 0; kt < 32; ++kt) { br0[kt] = w0[kt*64]; br1[kt] = w1[kt*64]; }
  }

  float c_reg[4] = {0,0,0,0}, bias_r[4] = {0,0,0,0};
  if (gh == 0) {
#pragma unroll
    for (int r = 0; r < 4; ++r)
      c_reg[r] = cbuf[(size_t)(tm*16 + bl0 + r) * F_DIM + fi];
#pragma unroll
    for (int g = 0; g < 4; ++g) bias_r[g] = bias[g * F_DIM + fi];
  }

  const bf8* apA = reinterpret_cast<const bf8*>(hp) + tm*64 + lane;          // read when p=0
  const bf8* apB = apA + 16384;                                              // read when p=1
  unsigned short* hwA = hp + 131072;     // write when p=0
  unsigned short* hwB = hp;              // write when p=1

  const ushort4* xw4 = reinterpret_cast<const ushort4*>(xwp);
  float* fc = out + (size_t)T_DIM * B_DIM * F_DIM;
  float* fh = fc + (size_t)B_DIM * F_DIM;

  for (int t = 0; t < CHUNK; ++t) {
    const bf8* ap = (t & 1) ? apB : apA;
    unsigned short* hw = (t & 1) ? hwB : hwA;
    f32x4 a0 = {0,0,0,0}, a1 = {0,0,0,0};
#pragma unroll
    for (int kt = 0; kt < 32; ++kt) {
      bf8 a = ap[kt*512];
      a0 = __builtin_amdgcn_mfma_f32_16x16x32_bf16(a, br0[kt], a0, 0, 0, 0);
      a1 = __builtin_amdgcn_mfma_f32_16x16x32_bf16(a, br1[kt], a1, 0, 0, 0);
    }
    if (gh == 1) {
#pragma unroll
      for (int r = 0; r < 4; ++r) {
        part[mtl][0][bl0 + r][lane & 15] = a0[r];
        part[mtl][1][bl0 + r][lane & 15] = a1[r];
      }
    }
    __syncthreads();
    if (gh == 0) {
      int tg = t0 + t;
      float xwf[4][4];
#pragma unroll
      for (int g = 0; g < 4; ++g) {
        ushort4 u = xw4[((size_t)(t*8 + tm)*256 + (g*64 + fg))*64 + lane];
        xwf[g][0] = bf2f(u.x); xwf[g][1] = bf2f(u.y);
        xwf[g][2] = bf2f(u.z); xwf[g][3] = bf2f(u.w);
      }
#pragma unroll
      for (int r = 0; r < 4; ++r) {
        int b = tm*16 + bl0 + r;
        int trm = term[tg * B_DIM + b];
        float hg0 = a0[r], hg1 = a1[r];
        float hg2 = part[mtl][0][bl0 + r][lane & 15];
        float hg3 = part[mtl][1][bl0 + r][lane & 15];
        float hx0 = xwf[0][r] + bias_r[0] + (trm ? 0.f : hg0);
        float hx1 = xwf[1][r] + bias_r[1] + (trm ? 0.f : hg1);
        float hx2 = xwf[2][r] + bias_r[2] + (trm ? 0.f : hg2);
        float hx3 = xwf[3][r] + bias_r[3] + (trm ? 0.f : hg3);
        float cp = trm ? 0.f : c_reg[r];
        float cn = sigm(hx1) * cp + sigm(hx0) * tanh_(hx2);
        float hn = sigm(hx3) * tanh_(cn);
        c_reg[r] = cn;
        out[((size_t)tg * B_DIM + b) * F_DIM + fi] = hn;
        int kt2 = fi >> 5;
        int l2  = (b & 15) | (((fi >> 3) & 3) << 4);
        hw[(size_t)((kt2*8 + tm)*64 + l2)*8 + (fi & 7)] = f2bf(hn);
        if (tg == T_DIM - 1) {
          fc[(size_t)b * F_DIM + fi] = cn;
          fh[(size_t)b * F_DIM + fi] = hn;
        }
      }
    }
    __syncthreads();
    if (tid == 0) {
      __hip_atomic_fetch_add(ctrl, 1u, __ATOMIC_RELEASE, __HIP_MEMORY_SCOPE_AGENT);
      unsigned int tgt = (unsigned int)NWGS * (unsigned int)(t + 1);
      while (__hip_atomic_load(ctrl, __ATOMIC_RELAXED, __HIP_MEMORY_SCOPE_AGENT) < tgt)
        __builtin_amdgcn_s_sleep(1);
      (void)__hip_atomic_load(ctrl, __ATOMIC_ACQUIRE, __HIP_MEMORY_SCOPE_AGENT);
    }
    __syncthreads();
  }
  if (gh == 0) {
#pragma unroll
    for (int r = 0; r < 4; ++r)
      cbuf[(size_t)(tm*16 + bl0 + r) * F_DIM + fi] = c_reg[r];
  }
}

extern "C" void kernel_launch(void* const* d_in, const int* in_sizes, int n_in,
                              void* d_out, int out_size, void* d_ws, size_t ws_size,
                              hipStream_t stream) {
  const float* x    = (const float*)d_in[0];
  const int*   term = (const int*)d_in[1];
  const float* c0   = (const float*)d_in[2];
  const float* h0   = (const float*)d_in[3];
  const float* Wi   = (const float*)d_in[4];
  const float* Wh   = (const float*)d_in[5];
  const float* bias = (const float*)d_in[6];
  float* out = (float*)d_out;
  char*  ws  = (char*)d_ws;

  if (ws_size < WS_NEED) return;

  unsigned int*   ctrl = (unsigned int*)(ws + OFF_CTRL);
  unsigned short* wip  = (unsigned short*)(ws + OFF_WIP);
  unsigned short* whp  = (unsigned short*)(ws + OFF_WHP);
  unsigned short* xp   = (unsigned short*)(ws + OFF_XP);
  unsigned short* xwp  = (unsigned short*)(ws + OFF_XWP);
  unsigned short* hp   = (unsigned short*)(ws + OFF_HP);
  float*          cbuf = (float*)(ws + OFF_CBUF);

  hipMemsetAsync(ctrl, 0, 1024, stream);
  pack_w<<<dim3(4096), dim3(256), 0, stream>>>(Wi, Wh, wip, whp);
  pack_h<<<dim3(64),   dim3(256), 0, stream>>>(h0, hp);
  hipMemcpyAsync(cbuf, c0, (size_t)B_DIM * F_DIM * sizeof(float),
                 hipMemcpyDeviceToDevice, stream);

  for (int c = 0; c < NCHUNK; ++c) {
    pack_x_chunk<<<dim3(2048), dim3(256), 0, stream>>>(
        x + (size_t)c * CHUNK * B_DIM * F_DIM, xp);
    xw_gemm<<<dim3(256), dim3(256), 0, stream>>>(xp, wip, xwp);
    lstm_scan<<<dim3(256), dim3(256), 0, stream>>>(
        xwp, whp, hp, bias, term, cbuf, out, ctrl + c, c * CHUNK);
  }
}

// Round 3
// 6666.993 us; speedup vs baseline: 1.1270x; 1.1270x over previous
//
#include <hip/hip_runtime.h>

#define T_DIM 256
#define B_DIM 128
#define F_DIM 1024
#define G_DIM 4096
#define NWGS  256

typedef short bf8  __attribute__((ext_vector_type(8)));
typedef float f32x4 __attribute__((ext_vector_type(4)));

// ---- ws layout (bytes) ----
#define OFF_FLAGS 0ull
#define OFF_WIP   4096ull
#define SZ_WPACK  (8ull*1024*1024)        // 256nt * 32kt * 64lane * 8 * 2B
#define OFF_WHP   (OFF_WIP + SZ_WPACK)
#define OFF_XPK   (OFF_WHP + SZ_WPACK)    // 256t * 32kt * 8mt * 64 * 8 * 2B = 64 MB
#define SZ_XPK    (64ull*1024*1024)
#define OFF_HP    (OFF_XPK + SZ_XPK)      // 2 * 128*1024 * 2B = 512 KB
#define WS_NEED   (OFF_HP + 2ull*131072ull*2ull)

__device__ __forceinline__ unsigned short f2bf(float v) {
  union { float f; unsigned int u; } c; c.f = v;
  unsigned int u = c.u;
  return (unsigned short)((u + 0x7fffu + ((u >> 16) & 1u)) >> 16);  // RNE
}
__device__ __forceinline__ float sigm(float x)  { return 1.f / (1.f + __expf(-x)); }
__device__ __forceinline__ float tanh_(float x) { return 1.f - 2.f / (1.f + __expf(2.f * x)); }

// ---- pack W (fp32 F x 4F) -> MFMA-B frag order bf16: frag idx (nt*32+kt)*64+lane ----
__global__ __launch_bounds__(256) void pack_w(const float* __restrict__ Wi,
                                              const float* __restrict__ Wh,
                                              unsigned short* __restrict__ wip,
                                              unsigned short* __restrict__ whp) {
  int gid = blockIdx.x * 256 + threadIdx.x;
  const float* src = (gid >= 524288) ? Wh : Wi;
  unsigned short* dst = (gid >= 524288) ? whp : wip;
  int r  = gid & 524287;
  int nt = r >> 11;
  int kt = (r >> 6) & 31;
  int l  = r & 63;
  int col = nt * 16 + (l & 15);
  int k0  = kt * 32 + ((l >> 4) << 3);
  bf8 v8;
#pragma unroll
  for (int j = 0; j < 8; ++j)
    v8[j] = (short)f2bf(src[(size_t)(k0 + j) * G_DIM + col]);
  *reinterpret_cast<bf8*>(dst + (size_t)r * 8) = v8;
}

// ---- pack all x (fp32 (T,B,F)) -> A-frag order [t][kt][mt][lane][8], coalesced reads ----
__global__ __launch_bounds__(256) void pack_x(const float* __restrict__ x,
                                              unsigned short* __restrict__ xpk) {
  int gid = blockIdx.x * 256 + threadIdx.x;   // T*B*128 = 4,194,304
  int fb = gid & 127;
  int b  = (gid >> 7) & 127;
  int t  = gid >> 14;
  const float* s = x + ((size_t)(t * B_DIM + b)) * F_DIM + fb * 8;
  float4 v0 = *reinterpret_cast<const float4*>(s);
  float4 v1 = *reinterpret_cast<const float4*>(s + 4);
  int kt = fb >> 2, j4 = fb & 3, mt = b >> 4;
  int lane2 = (b & 15) | (j4 << 4);
  bf8 o;
  o[0] = (short)f2bf(v0.x); o[1] = (short)f2bf(v0.y);
  o[2] = (short)f2bf(v0.z); o[3] = (short)f2bf(v0.w);
  o[4] = (short)f2bf(v1.x); o[5] = (short)f2bf(v1.y);
  o[6] = (short)f2bf(v1.z); o[7] = (short)f2bf(v1.w);
  *reinterpret_cast<bf8*>(xpk + ((size_t)(((t * 32 + kt) * 8 + mt) * 64) + lane2) * 8) = o;
}

// ---- h0 fp32 -> bf16 row-major into h buffer 0 ----
__global__ __launch_bounds__(256) void pack_h(const float* __restrict__ h0,
                                              unsigned short* __restrict__ hp) {
  int i = blockIdx.x * 256 + threadIdx.x;     // 131072
  hp[i] = f2bf(h0[i]);
}

// ---- persistent 256-step scan: 256 WGs x 256 thr; Wh in regs; x@Wi inline ----
__global__ __launch_bounds__(256, 1) void lstm_scan(
    const unsigned short* __restrict__ xpk,
    const unsigned short* __restrict__ wip,
    const unsigned short* __restrict__ whp,
    unsigned short* __restrict__ hp,            // [2][128][1024] bf16
    const float* __restrict__ bias,
    const int*   __restrict__ term,
    const float* __restrict__ c0,
    float* __restrict__ out,
    unsigned int* __restrict__ flags) {
  __shared__ float part[2][2][16][17];          // [mtl][gate 2,3][row][col]

  const int fg   = blockIdx.x & 63;
  const int mq4  = blockIdx.x >> 6;             // 0..3
  const int tid  = threadIdx.x;
  const int wv   = tid >> 6, lane = tid & 63;
  const int gh   = wv >> 1, mtl = wv & 1;
  const int tm   = mq4 * 2 + mtl;               // 0..7
  const int col  = lane & 15;
  const int kq   = lane >> 4;                   // 0..3
  const int fi   = fg * 16 + col;
  const int bl0  = kq * 4;
  const int arow = tm * 16 + col;               // A-frag row for this lane

  // Wh fragments resident in registers (2 gate-columns of 32 kt frags)
  const int nt0 = (gh * 2 + 0) * 64 + fg;
  const int nt1 = (gh * 2 + 1) * 64 + fg;
  const bf8* wf  = reinterpret_cast<const bf8*>(whp);
  const bf8* wif = reinterpret_cast<const bf8*>(wip);
  bf8 wh0[32], wh1[32];
#pragma unroll
  for (int kt = 0; kt < 32; ++kt) {
    wh0[kt] = wf[(size_t)(nt0 * 32 + kt) * 64 + lane];
    wh1[kt] = wf[(size_t)(nt1 * 32 + kt) * 64 + lane];
  }

  float c_reg[4] = {0, 0, 0, 0}, bias_r[4] = {0, 0, 0, 0};
  if (gh == 0) {
#pragma unroll
    for (int r = 0; r < 4; ++r)
      c_reg[r] = c0[(size_t)(tm * 16 + bl0 + r) * F_DIM + fi];
#pragma unroll
    for (int g = 0; g < 4; ++g) bias_r[g] = bias[g * F_DIM + fi];
  }

  float* fc = out + (size_t)T_DIM * B_DIM * F_DIM;
  float* fh = fc + (size_t)B_DIM * F_DIM;

#pragma unroll 1
  for (int t = 0; t < T_DIM; ++t) {
    // ---- wait for all WGs to have published h for this step (t>0) ----
    if (t > 0) {
      unsigned int tgt = (unsigned int)t;
      for (;;) {
        unsigned int f0 = __hip_atomic_load(flags + lane,       __ATOMIC_RELAXED, __HIP_MEMORY_SCOPE_AGENT);
        unsigned int f1 = __hip_atomic_load(flags + 64 + lane,  __ATOMIC_RELAXED, __HIP_MEMORY_SCOPE_AGENT);
        unsigned int f2 = __hip_atomic_load(flags + 128 + lane, __ATOMIC_RELAXED, __HIP_MEMORY_SCOPE_AGENT);
        unsigned int f3 = __hip_atomic_load(flags + 192 + lane, __ATOMIC_RELAXED, __HIP_MEMORY_SCOPE_AGENT);
        bool ok = (f0 >= tgt) & (f1 >= tgt) & (f2 >= tgt) & (f3 >= tgt);
        if (__all(ok)) break;
        __builtin_amdgcn_s_sleep(1);
      }
      asm volatile("" ::: "memory");
    }

    const int trm = term[t * B_DIM + arow];

    // ---- x @ Wi (Wi streamed, L2/LLC-resident) ----
    f32x4 acc0 = {0, 0, 0, 0}, acc1 = {0, 0, 0, 0};
    const bf8* xf = reinterpret_cast<const bf8*>(xpk) + ((size_t)t * 256 + tm) * 64 + lane;
#pragma unroll
    for (int kt = 0; kt < 32; ++kt) {
      bf8 a = xf[(size_t)kt * 512];
      acc0 = __builtin_amdgcn_mfma_f32_16x16x32_bf16(a, wif[(size_t)(nt0 * 32 + kt) * 64 + lane], acc0, 0, 0, 0);
      acc1 = __builtin_amdgcn_mfma_f32_16x16x32_bf16(a, wif[(size_t)(nt1 * 32 + kt) * 64 + lane], acc1, 0, 0, 0);
    }

    // ---- h A-frags: coherent 8B loads from LLC, masked by termination ----
    const unsigned short* hb = hp + (size_t)(t & 1) * 131072;
    const unsigned long long* hq =
        reinterpret_cast<const unsigned long long*>(hb + (size_t)arow * 1024) + kq * 2;
    unsigned long long hvlo[32], hvhi[32];
#pragma unroll
    for (int kt = 0; kt < 32; ++kt) {
      hvlo[kt] = __hip_atomic_load(const_cast<unsigned long long*>(hq + kt * 8),
                                   __ATOMIC_RELAXED, __HIP_MEMORY_SCOPE_AGENT);
      hvhi[kt] = __hip_atomic_load(const_cast<unsigned long long*>(hq + kt * 8 + 1),
                                   __ATOMIC_RELAXED, __HIP_MEMORY_SCOPE_AGENT);
    }
    // ---- h @ Wh (weights in registers) ----
#pragma unroll
    for (int kt = 0; kt < 32; ++kt) {
      union { unsigned long long q[2]; bf8 v; } u;
      u.q[0] = trm ? 0ull : hvlo[kt];
      u.q[1] = trm ? 0ull : hvhi[kt];
      acc0 = __builtin_amdgcn_mfma_f32_16x16x32_bf16(u.v, wh0[kt], acc0, 0, 0, 0);
      acc1 = __builtin_amdgcn_mfma_f32_16x16x32_bf16(u.v, wh1[kt], acc1, 0, 0, 0);
    }

    // ---- gate exchange + epilogue ----
    if (gh == 1) {
#pragma unroll
      for (int r = 0; r < 4; ++r) {
        part[mtl][0][bl0 + r][col] = acc0[r];
        part[mtl][1][bl0 + r][col] = acc1[r];
      }
    }
    __syncthreads();
    if (gh == 0) {
      unsigned short* hw = hp + (size_t)((t + 1) & 1) * 131072;
#pragma unroll
      for (int r = 0; r < 4; ++r) {
        int b = tm * 16 + bl0 + r;
        int trmR = term[t * B_DIM + b];
        float vi = acc0[r] + bias_r[0];
        float vf = acc1[r] + bias_r[1];
        float vg = part[mtl][0][bl0 + r][col] + bias_r[2];
        float vo = part[mtl][1][bl0 + r][col] + bias_r[3];
        float cp = trmR ? 0.f : c_reg[r];
        float cn = sigm(vf) * cp + sigm(vi) * tanh_(vg);
        float hn = sigm(vo) * tanh_(cn);
        c_reg[r] = cn;
        out[((size_t)t * B_DIM + b) * F_DIM + fi] = hn;
        unsigned int mybits = f2bf(hn);
        unsigned int nbr = (unsigned int)__shfl_xor((int)mybits, 1, 64);
        if (!(lane & 1)) {
          unsigned int pk = mybits | (nbr << 16);
          __hip_atomic_store(reinterpret_cast<unsigned int*>(hw + (size_t)b * 1024 + (fi & ~1)),
                             pk, __ATOMIC_RELAXED, __HIP_MEMORY_SCOPE_AGENT);
        }
        if (t == T_DIM - 1) {
          fc[(size_t)b * F_DIM + fi] = cn;
          fh[(size_t)b * F_DIM + fi] = hn;
        }
      }
    }
    __syncthreads();   // drains h stores (vmcnt 0) before flag publish
    if (tid == 0)
      __hip_atomic_store(flags + blockIdx.x, (unsigned int)(t + 1),
                         __ATOMIC_RELAXED, __HIP_MEMORY_SCOPE_AGENT);
  }
}

extern "C" void kernel_launch(void* const* d_in, const int* in_sizes, int n_in,
                              void* d_out, int out_size, void* d_ws, size_t ws_size,
                              hipStream_t stream) {
  const float* x    = (const float*)d_in[0];
  const int*   term = (const int*)d_in[1];
  const float* c0   = (const float*)d_in[2];
  const float* h0   = (const float*)d_in[3];
  const float* Wi   = (const float*)d_in[4];
  const float* Wh   = (const float*)d_in[5];
  const float* bias = (const float*)d_in[6];
  float* out = (float*)d_out;
  char*  ws  = (char*)d_ws;

  if (ws_size < WS_NEED) return;

  unsigned int*   flags = (unsigned int*)(ws + OFF_FLAGS);
  unsigned short* wip   = (unsigned short*)(ws + OFF_WIP);
  unsigned short* whp   = (unsigned short*)(ws + OFF_WHP);
  unsigned short* xpk   = (unsigned short*)(ws + OFF_XPK);
  unsigned short* hp    = (unsigned short*)(ws + OFF_HP);

  hipMemsetAsync(flags, 0, 1024, stream);
  pack_w<<<dim3(4096),  dim3(256), 0, stream>>>(Wi, Wh, wip, whp);
  pack_x<<<dim3(16384), dim3(256), 0, stream>>>(x, xpk);
  pack_h<<<dim3(512),   dim3(256), 0, stream>>>(h0, hp);
  lstm_scan<<<dim3(NWGS), dim3(256), 0, stream>>>(xpk, wip, whp, hp, bias, term, c0, out, flags);
}